// Round 8
// baseline (342.993 us; speedup 1.0000x reference)
//
#include <hip/hip_runtime.h>
#include <cstdint>

#define N_SAMPLES 16384
#define DIM 2048
#define PDIM 256
#define NB 32
#define NL 100
#define NSEG (NB * NL)

typedef float floatx4 __attribute__((ext_vector_type(4)));
typedef __bf16 bf16x8 __attribute__((ext_vector_type(8)));

__device__ __forceinline__ unsigned short f32_to_bf16(float f) {
    unsigned int u = __float_as_uint(f);
    u += 0x7fffu + ((u >> 16) & 1u);   // round-to-nearest-even
    return (unsigned short)(u >> 16);
}
__device__ __forceinline__ unsigned int pack_bf16x2(float a, float b) {
    return (unsigned int)f32_to_bf16(a) | ((unsigned int)f32_to_bf16(b) << 16);
}

// ---------------------------------------------------------------------------
// prep: Wbf = [W1;W2] -> bf16 (512x2048), bias sum, seg index,
//       zero cnt + SW2 + out (out/SW2 are atomicAdd targets of the GEMM).
// ---------------------------------------------------------------------------
__global__ __launch_bounds__(256) void prep_kernel(
    const float* __restrict__ W1w, const float* __restrict__ W1b,
    const float* __restrict__ W2w, const float* __restrict__ W2b,
    const int* __restrict__ label, const int* __restrict__ lbatch,
    unsigned short* __restrict__ Wbf, float* __restrict__ bias,
    int* __restrict__ seg, int* __restrict__ cnt, float* __restrict__ SW2,
    float* __restrict__ out)
{
    int i = blockIdx.x * 256 + threadIdx.x;   // grid = PDIM*DIM threads (524288)
    Wbf[i]              = f32_to_bf16(W1w[i]);
    Wbf[PDIM * DIM + i] = f32_to_bf16(W2w[i]);
    if (i < PDIM) bias[i] = W1b[i] + W2b[i];
    if (i < N_SAMPLES) seg[i] = lbatch[i] * NL + label[i];
    if (i < NSEG) cnt[i] = 0;
    if (i < NSEG * PDIM / 2) ((float2*)SW2)[i] = make_float2(0.f, 0.f);
    // out: N*PDIM floats = 1M float4 = 2 per thread
    const float4 z4 = make_float4(0.f, 0.f, 0.f, 0.f);
    ((float4*)out)[2 * i]     = z4;
    ((float4*)out)[2 * i + 1] = z4;
}

__global__ __launch_bounds__(256) void hist_kernel(
    const int* __restrict__ seg, int* __restrict__ cnt)
{
    int i = blockIdx.x * 256 + threadIdx.x;
    atomicAdd(&cnt[seg[i]], 1);
}

// ---------------------------------------------------------------------------
// xconv: x f32 -> xb bf16, streaming. 32B/lane in, 16B/lane out, coalesced.
// Pure BW-bound (192 MB). Makes A eligible for global_load_lds staging.
// ---------------------------------------------------------------------------
__global__ __launch_bounds__(256) void xconv_kernel(
    const float* __restrict__ x, unsigned short* __restrict__ xb)
{
    const size_t idx = (size_t)blockIdx.x * 256 + threadIdx.x;  // N*D/8 threads
    const float4 a0 = *(const float4*)(x + idx * 8);
    const float4 a1 = *(const float4*)(x + idx * 8 + 4);
    uint4 o;
    o.x = pack_bf16x2(a0.x, a0.y);
    o.y = pack_bf16x2(a0.z, a0.w);
    o.z = pack_bf16x2(a1.x, a1.y);
    o.w = pack_bf16x2(a1.z, a1.w);
    *(uint4*)(xb + idx * 8) = o;
}

// ---------------------------------------------------------------------------
// GEMM (m97 structure, 128x128 tile, 4 waves 2x2, 16 MFMA/K-step, pure
// global_load_lds staging, classic 2-barrier loop), split-K=2:
//   C[16384, 512] = xb @ [W1;W2]^T
// grid = 1024 WGs (1D) = 4 blocks/CU — the occupancy regime where this
// structure measured 874 TF (m97/m103).  Decode groups blocks that are
// congruent mod 8 (same XCD under round-robin dispatch) into a 16-m-tile
// band, so A-tiles are served from one XCD's L2 (T1 swizzle).
// cols   0..255 (W1): atomicAdd into pre-zeroed out (2 adds/address)
// cols 256..511 (W2): atomicAdd into SW2[seg[row]] (linearity: segment sums)
// ---------------------------------------------------------------------------
__global__ __launch_bounds__(256) void gemm512_kernel(
    const unsigned short* __restrict__ A,    // xb [16384,2048]
    const unsigned short* __restrict__ Wbf,  // [512,2048]
    const int* __restrict__ seg,
    float* __restrict__ out, float* __restrict__ SW2)
{
    constexpr int BM = 128, BN = 128, BK = 32, KS = 2;
    __shared__ __align__(16) unsigned short ldsA[BM * BK];   // 8 KB
    __shared__ __align__(16) unsigned short ldsB[BN * BK];   // 8 KB
    const int tid = threadIdx.x;
    const int lane = tid & 63;
    const int wave = tid >> 6;
    const int wr = wave >> 1, wc = wave & 1;   // 2x2 waves, 64x64 subtile
    const int quad = lane >> 4, l15 = lane & 15;

    // XCD-grouped decode: bid ≡ j (mod 8) -> XCD j -> m-tiles [j*16, j*16+16)
    const int bid = blockIdx.x;                // 0..1023
    const int j = bid & 7;
    const int idx = bid >> 3;                  // 0..127
    const int m0 = (j * 16 + (idx & 15)) * BM; // 128 m-tiles
    const int nz = idx >> 4;                   // 0..7
    const int n0 = (nz & 3) * BN;              // 0,128,256,384
    const int z  = nz >> 2;                    // K-slice 0,1
    const int k0 = z * (DIM / KS);
    const int srow = lane >> 2, schunk = lane & 3;

    floatx4 acc[4][4];
    #pragma unroll
    for (int i = 0; i < 4; ++i)
        #pragma unroll
        for (int jj = 0; jj < 4; ++jj) acc[i][jj] = (floatx4){0.f, 0.f, 0.f, 0.f};

    const unsigned short* Abase = A + (size_t)(m0 + srow) * DIM + schunk * 8;
    const unsigned short* Bbase = Wbf + (size_t)(n0 + srow) * DIM + schunk * 8;

    for (int kk = k0; kk < k0 + DIM / KS; kk += BK) {
        __syncthreads();
        #pragma unroll
        for (int ch = wave; ch < BM / 16; ch += 4)
            __builtin_amdgcn_global_load_lds(
                (const __attribute__((address_space(1))) void*)(Abase + (size_t)ch * 16 * DIM + kk),
                (__attribute__((address_space(3))) void*)&ldsA[ch * 16 * BK], 16, 0, 0);
        #pragma unroll
        for (int ch = wave; ch < BN / 16; ch += 4)
            __builtin_amdgcn_global_load_lds(
                (const __attribute__((address_space(1))) void*)(Bbase + (size_t)ch * 16 * DIM + kk),
                (__attribute__((address_space(3))) void*)&ldsB[ch * 16 * BK], 16, 0, 0);
        __syncthreads();

        bf16x8 af[4], bf[4];
        #pragma unroll
        for (int mi = 0; mi < 4; ++mi)
            af[mi] = *(const bf16x8*)&ldsA[(wr * 64 + mi * 16 + l15) * BK + quad * 8];
        #pragma unroll
        for (int ni = 0; ni < 4; ++ni)
            bf[ni] = *(const bf16x8*)&ldsB[(wc * 64 + ni * 16 + l15) * BK + quad * 8];
        #pragma unroll
        for (int mi = 0; mi < 4; ++mi)
            #pragma unroll
            for (int ni = 0; ni < 4; ++ni)
                acc[mi][ni] = __builtin_amdgcn_mfma_f32_16x16x32_bf16(
                    af[mi], bf[ni], acc[mi][ni], 0, 0, 0);
    }

    if (n0 < PDIM) {                           // W1 half -> out (pre-zeroed)
        #pragma unroll
        for (int mi = 0; mi < 4; ++mi) {
            const int rbase = m0 + wr * 64 + mi * 16 + quad * 4;
            #pragma unroll
            for (int ni = 0; ni < 4; ++ni) {
                const int col = n0 + wc * 64 + ni * 16 + l15;
                #pragma unroll
                for (int r = 0; r < 4; ++r)
                    atomicAdd(&out[(size_t)(rbase + r) * PDIM + col], acc[mi][ni][r]);
            }
        }
    } else {                                   // W2 half -> SW2[seg] atomics
        const int c0 = n0 - PDIM;
        #pragma unroll
        for (int mi = 0; mi < 4; ++mi) {
            const int rbase = m0 + wr * 64 + mi * 16 + quad * 4;
            #pragma unroll
            for (int r = 0; r < 4; ++r) {
                const int sr = seg[rbase + r];
                #pragma unroll
                for (int ni = 0; ni < 4; ++ni) {
                    const int col = c0 + wc * 64 + ni * 16 + l15;
                    atomicAdd(&SW2[(size_t)sr * PDIM + col], acc[mi][ni][r]);
                }
            }
        }
    }
}

// ---------------------------------------------------------------------------
// finalize: SW2[s,col] <- (BW2[b,col] - SW2[s,col]) / dc   (in place)
// BW2[b] = sum over the batch's 100 label-rows of SW2 (linearity),
// dc = batch count - segment count (zero-guarded like the reference).
// ---------------------------------------------------------------------------
__global__ __launch_bounds__(256) void finalize_kernel(
    float* __restrict__ SW2, const int* __restrict__ cnt)
{
    const int b = blockIdx.x;        // 0..31
    const int col = threadIdx.x;     // 0..255
    int cb = 0;
    #pragma unroll 4
    for (int l = 0; l < NL; ++l) cb += cnt[b * NL + l];
    float tot = 0.f;
    #pragma unroll 4
    for (int l = 0; l < NL; ++l)
        tot += SW2[(size_t)(b * NL + l) * PDIM + col];
    for (int l = 0; l < NL; ++l) {
        const int s = b * NL + l;
        const int dc = cb - cnt[s];
        const float v = SW2[(size_t)s * PDIM + col];
        SW2[(size_t)s * PDIM + col] = (dc > 0) ? (tot - v) / (float)dc : 0.f;
    }
}

// ---------------------------------------------------------------------------
// epilogue: out[i,:] += bias + SW2[seg[i],:]   (float4 per thread)
// ---------------------------------------------------------------------------
__global__ __launch_bounds__(256) void epilogue_kernel(
    float* __restrict__ out, const float* __restrict__ SW2,
    const float* __restrict__ bias, const int* __restrict__ seg)
{
    const int idx = blockIdx.x * 256 + threadIdx.x;   // over N*PDIM/4
    const int row = idx >> 6;                         // 64 float4 per row
    const int c = (idx & 63) * 4;
    float4 v = ((const float4*)out)[idx];
    const float4 b4 = *(const float4*)&bias[c];
    const float4 s4 = *(const float4*)&SW2[(size_t)seg[row] * PDIM + c];
    v.x += b4.x + s4.x; v.y += b4.y + s4.y;
    v.z += b4.z + s4.z; v.w += b4.w + s4.w;
    ((float4*)out)[idx] = v;
}

// ---------------------------------------------------------------------------
extern "C" void kernel_launch(void* const* d_in, const int* in_sizes, int n_in,
                              void* d_out, int out_size, void* d_ws, size_t ws_size,
                              hipStream_t stream)
{
    const float* x      = (const float*)d_in[0];
    const int*   label  = (const int*)d_in[1];
    const int*   lbatch = (const int*)d_in[2];
    const float* W1w    = (const float*)d_in[3];
    const float* W1b    = (const float*)d_in[4];
    const float* W2w    = (const float*)d_in[5];
    const float* W2b    = (const float*)d_in[6];
    float* out = (float*)d_out;

    char* ws = (char*)d_ws;
    size_t off = 0;
    auto alloc = [&](size_t bytes) {
        void* p = ws + off;
        off = (off + bytes + 255) & ~(size_t)255;
        return p;
    };
    unsigned short* xb  = (unsigned short*)alloc((size_t)N_SAMPLES * DIM * 2); // 64 MB
    unsigned short* Wbf = (unsigned short*)alloc((size_t)2 * PDIM * DIM * 2);  // 2 MB
    float* SW2  = (float*)alloc((size_t)NSEG * PDIM * 4);                      // 3.3 MB
    float* bias = (float*)alloc(PDIM * 4);
    int*   seg  = (int*)alloc(N_SAMPLES * 4);
    int*   cnt  = (int*)alloc(NSEG * 4);

    prep_kernel<<<PDIM * DIM / 256, 256, 0, stream>>>(
        W1w, W1b, W2w, W2b, label, lbatch, Wbf, bias, seg, cnt, SW2, out);

    hist_kernel<<<N_SAMPLES / 256, 256, 0, stream>>>(seg, cnt);

    xconv_kernel<<<(size_t)N_SAMPLES * DIM / 8 / 256, 256, 0, stream>>>(x, xb);

    // out += xb@W1^T (atomic, 2 K-slices) ; SW2[s] += xb@W2^T segment rows
    gemm512_kernel<<<1024, 256, 0, stream>>>(xb, Wbf, seg, out, SW2);

    // SW2[s] <- (batch-total - SW2[s]) / dc   (LOO mean @ W2^T, by linearity)
    finalize_kernel<<<NB, 256, 0, stream>>>(SW2, cnt);

    // out += bias + SW2[seg]
    epilogue_kernel<<<(size_t)N_SAMPLES * PDIM / 4 / 256, 256, 0, stream>>>(
        out, SW2, bias, seg);
}

// Round 9
// 322.929 us; speedup vs baseline: 1.0621x; 1.0621x over previous
//
#include <hip/hip_runtime.h>
#include <cstdint>

#define N_SAMPLES 16384
#define DIM 2048
#define PDIM 256
#define NB 32
#define NL 100
#define NSEG (NB * NL)

typedef float floatx4 __attribute__((ext_vector_type(4)));
typedef __bf16 bf16x8 __attribute__((ext_vector_type(8)));

__device__ __forceinline__ unsigned short f32_to_bf16(float f) {
    unsigned int u = __float_as_uint(f);
    u += 0x7fffu + ((u >> 16) & 1u);   // round-to-nearest-even
    return (unsigned short)(u >> 16);
}
__device__ __forceinline__ unsigned int pack_bf16x2(float a, float b) {
    return (unsigned int)f32_to_bf16(a) | ((unsigned int)f32_to_bf16(b) << 16);
}

// ---------------------------------------------------------------------------
// prep: Wbf = [W1;W2] -> bf16 (512x2048), bias sum, seg index, zero cnt + SW2
// ---------------------------------------------------------------------------
__global__ __launch_bounds__(256) void prep_kernel(
    const float* __restrict__ W1w, const float* __restrict__ W1b,
    const float* __restrict__ W2w, const float* __restrict__ W2b,
    const int* __restrict__ label, const int* __restrict__ lbatch,
    unsigned short* __restrict__ Wbf, float* __restrict__ bias,
    int* __restrict__ seg, int* __restrict__ cnt, float* __restrict__ SW2)
{
    int i = blockIdx.x * 256 + threadIdx.x;   // grid = PDIM*DIM threads
    Wbf[i]              = f32_to_bf16(W1w[i]);
    Wbf[PDIM * DIM + i] = f32_to_bf16(W2w[i]);
    if (i < PDIM) bias[i] = W1b[i] + W2b[i];
    if (i < N_SAMPLES) seg[i] = lbatch[i] * NL + label[i];
    if (i < NSEG) cnt[i] = 0;
    if (i < NSEG * PDIM / 2) ((float2*)SW2)[i] = make_float2(0.f, 0.f);
}

__global__ __launch_bounds__(256) void hist_kernel(
    const int* __restrict__ seg, int* __restrict__ cnt)
{
    int i = blockIdx.x * 256 + threadIdx.x;
    atomicAdd(&cnt[seg[i]], 1);
}

// ---------------------------------------------------------------------------
// xconv: x f32 -> xb bf16, streaming. 32B/lane in, 16B/lane out, coalesced.
// Pure BW-bound (192 MB). Makes A eligible for global_load_lds staging.
// ---------------------------------------------------------------------------
__global__ __launch_bounds__(256) void xconv_kernel(
    const float* __restrict__ x, unsigned short* __restrict__ xb)
{
    const size_t idx = (size_t)blockIdx.x * 256 + threadIdx.x;  // N*D/8 threads
    const float4 a0 = *(const float4*)(x + idx * 8);
    const float4 a1 = *(const float4*)(x + idx * 8 + 4);
    uint4 o;
    o.x = pack_bf16x2(a0.x, a0.y);
    o.y = pack_bf16x2(a0.z, a0.w);
    o.z = pack_bf16x2(a1.x, a1.y);
    o.w = pack_bf16x2(a1.z, a1.w);
    *(uint4*)(xb + idx * 8) = o;
}

// ---------------------------------------------------------------------------
// GEMM (m97 structure, 128x128 tile, 4 waves 2x2, 16 MFMA/K-step, pure
// global_load_lds staging, classic 2-barrier loop), split-K=2 with
// DETERMINISTIC partial buffers (no out atomics — R8's regression):
//   C[16384, 512] = xb @ [W1;W2]^T
// grid = (128, 4, 2) = 1024 WGs = 4 blocks/CU — the co-residency regime
// where this structure measured 833-912 TF (m102/m103: 1/CU=320, 4/CU=833).
// cols   0..255 (W1): outp[z][row][col] = partial  (coalesced stores)
// cols 256..511 (W2): atomicAdd(SW2[seg[row]][col-256]) (cheap: ~8 writers)
// ---------------------------------------------------------------------------
__global__ __launch_bounds__(256) void gemm512_kernel(
    const unsigned short* __restrict__ A,    // xb [16384,2048]
    const unsigned short* __restrict__ Wbf,  // [512,2048]
    const int* __restrict__ seg,
    float* __restrict__ outp,                // [2][N_SAMPLES][PDIM]
    float* __restrict__ SW2)
{
    constexpr int BM = 128, BN = 128, BK = 32, KS = 2;
    __shared__ __align__(16) unsigned short ldsA[BM * BK];   // 8 KB
    __shared__ __align__(16) unsigned short ldsB[BN * BK];   // 8 KB
    const int tid = threadIdx.x;
    const int lane = tid & 63;
    const int wave = tid >> 6;
    const int wr = wave >> 1, wc = wave & 1;   // 2x2 waves, 64x64 subtile
    const int quad = lane >> 4, l15 = lane & 15;
    const int m0 = blockIdx.x * BM;
    const int n0 = blockIdx.y * BN;            // 0,128,256,384
    const int z = blockIdx.z;                  // K-slice
    const int k0 = z * (DIM / KS);
    const int srow = lane >> 2, schunk = lane & 3;

    floatx4 acc[4][4];
    #pragma unroll
    for (int i = 0; i < 4; ++i)
        #pragma unroll
        for (int j = 0; j < 4; ++j) acc[i][j] = (floatx4){0.f, 0.f, 0.f, 0.f};

    const unsigned short* Abase = A + (size_t)(m0 + srow) * DIM + schunk * 8;
    const unsigned short* Bbase = Wbf + (size_t)(n0 + srow) * DIM + schunk * 8;

    for (int kk = k0; kk < k0 + DIM / KS; kk += BK) {
        __syncthreads();
        #pragma unroll
        for (int ch = wave; ch < BM / 16; ch += 4)
            __builtin_amdgcn_global_load_lds(
                (const __attribute__((address_space(1))) void*)(Abase + (size_t)ch * 16 * DIM + kk),
                (__attribute__((address_space(3))) void*)&ldsA[ch * 16 * BK], 16, 0, 0);
        #pragma unroll
        for (int ch = wave; ch < BN / 16; ch += 4)
            __builtin_amdgcn_global_load_lds(
                (const __attribute__((address_space(1))) void*)(Bbase + (size_t)ch * 16 * DIM + kk),
                (__attribute__((address_space(3))) void*)&ldsB[ch * 16 * BK], 16, 0, 0);
        __syncthreads();

        bf16x8 af[4], bf[4];
        #pragma unroll
        for (int mi = 0; mi < 4; ++mi)
            af[mi] = *(const bf16x8*)&ldsA[(wr * 64 + mi * 16 + l15) * BK + quad * 8];
        #pragma unroll
        for (int ni = 0; ni < 4; ++ni)
            bf[ni] = *(const bf16x8*)&ldsB[(wc * 64 + ni * 16 + l15) * BK + quad * 8];
        #pragma unroll
        for (int mi = 0; mi < 4; ++mi)
            #pragma unroll
            for (int ni = 0; ni < 4; ++ni)
                acc[mi][ni] = __builtin_amdgcn_mfma_f32_16x16x32_bf16(
                    af[mi], bf[ni], acc[mi][ni], 0, 0, 0);
    }

    if (n0 < PDIM) {                           // W1 half -> outp[z], coalesced
        float* op = outp + (size_t)z * N_SAMPLES * PDIM;
        #pragma unroll
        for (int mi = 0; mi < 4; ++mi) {
            const int rbase = m0 + wr * 64 + mi * 16 + quad * 4;
            #pragma unroll
            for (int ni = 0; ni < 4; ++ni) {
                const int col = n0 + wc * 64 + ni * 16 + l15;
                #pragma unroll
                for (int r = 0; r < 4; ++r)
                    op[(size_t)(rbase + r) * PDIM + col] = acc[mi][ni][r];
            }
        }
    } else {                                   // W2 half -> SW2[seg] atomics
        const int c0 = n0 - PDIM;
        #pragma unroll
        for (int mi = 0; mi < 4; ++mi) {
            const int rbase = m0 + wr * 64 + mi * 16 + quad * 4;
            #pragma unroll
            for (int r = 0; r < 4; ++r) {
                const int sr = seg[rbase + r];
                #pragma unroll
                for (int ni = 0; ni < 4; ++ni) {
                    const int col = c0 + wc * 64 + ni * 16 + l15;
                    atomicAdd(&SW2[(size_t)sr * PDIM + col], acc[mi][ni][r]);
                }
            }
        }
    }
}

// ---------------------------------------------------------------------------
// finalize: SW2[s,col] <- (BW2[b,col] - SW2[s,col]) / dc   (in place)
// BW2[b] = sum over the batch's 100 label-rows of SW2 (linearity),
// dc = batch count - segment count (zero-guarded like the reference).
// ---------------------------------------------------------------------------
__global__ __launch_bounds__(256) void finalize_kernel(
    float* __restrict__ SW2, const int* __restrict__ cnt)
{
    const int b = blockIdx.x;        // 0..31
    const int col = threadIdx.x;     // 0..255
    int cb = 0;
    #pragma unroll 4
    for (int l = 0; l < NL; ++l) cb += cnt[b * NL + l];
    float tot = 0.f;
    #pragma unroll 4
    for (int l = 0; l < NL; ++l)
        tot += SW2[(size_t)(b * NL + l) * PDIM + col];
    for (int l = 0; l < NL; ++l) {
        const int s = b * NL + l;
        const int dc = cb - cnt[s];
        const float v = SW2[(size_t)s * PDIM + col];
        SW2[(size_t)s * PDIM + col] = (dc > 0) ? (tot - v) / (float)dc : 0.f;
    }
}

// ---------------------------------------------------------------------------
// epilogue: out = outp[0] + outp[1] + bias + SW2[seg]   (float4 per thread)
// ---------------------------------------------------------------------------
__global__ __launch_bounds__(256) void epilogue_kernel(
    float* __restrict__ out, const float* __restrict__ outp,
    const float* __restrict__ SW2, const float* __restrict__ bias,
    const int* __restrict__ seg)
{
    const int idx = blockIdx.x * 256 + threadIdx.x;   // over N*PDIM/4
    const int row = idx >> 6;                         // 64 float4 per row
    const int c = (idx & 63) * 4;
    float4 v0 = ((const float4*)outp)[idx];
    float4 v1 = ((const float4*)outp)[idx + N_SAMPLES * PDIM / 4];
    const float4 b4 = *(const float4*)&bias[c];
    const float4 s4 = *(const float4*)&SW2[(size_t)seg[row] * PDIM + c];
    float4 o;
    o.x = v0.x + v1.x + b4.x + s4.x;
    o.y = v0.y + v1.y + b4.y + s4.y;
    o.z = v0.z + v1.z + b4.z + s4.z;
    o.w = v0.w + v1.w + b4.w + s4.w;
    ((float4*)out)[idx] = o;
}

// ---------------------------------------------------------------------------
extern "C" void kernel_launch(void* const* d_in, const int* in_sizes, int n_in,
                              void* d_out, int out_size, void* d_ws, size_t ws_size,
                              hipStream_t stream)
{
    const float* x      = (const float*)d_in[0];
    const int*   label  = (const int*)d_in[1];
    const int*   lbatch = (const int*)d_in[2];
    const float* W1w    = (const float*)d_in[3];
    const float* W1b    = (const float*)d_in[4];
    const float* W2w    = (const float*)d_in[5];
    const float* W2b    = (const float*)d_in[6];
    float* out = (float*)d_out;

    char* ws = (char*)d_ws;
    size_t off = 0;
    auto alloc = [&](size_t bytes) {
        void* p = ws + off;
        off = (off + bytes + 255) & ~(size_t)255;
        return p;
    };
    unsigned short* xb  = (unsigned short*)alloc((size_t)N_SAMPLES * DIM * 2); // 64 MB
    float* outp = (float*)alloc((size_t)2 * N_SAMPLES * PDIM * 4);             // 32 MB
    unsigned short* Wbf = (unsigned short*)alloc((size_t)2 * PDIM * DIM * 2);  // 2 MB
    float* SW2  = (float*)alloc((size_t)NSEG * PDIM * 4);                      // 3.3 MB
    float* bias = (float*)alloc(PDIM * 4);
    int*   seg  = (int*)alloc(N_SAMPLES * 4);
    int*   cnt  = (int*)alloc(NSEG * 4);

    prep_kernel<<<PDIM * DIM / 256, 256, 0, stream>>>(
        W1w, W1b, W2w, W2b, label, lbatch, Wbf, bias, seg, cnt, SW2);

    hist_kernel<<<N_SAMPLES / 256, 256, 0, stream>>>(seg, cnt);

    xconv_kernel<<<(size_t)N_SAMPLES * DIM / 8 / 256, 256, 0, stream>>>(x, xb);

    // outp[z] = xb@W1^T K-slice z ; SW2[s] += xb@W2^T segment rows
    gemm512_kernel<<<dim3(N_SAMPLES / 128, 4, 2), 256, 0, stream>>>(
        xb, Wbf, seg, outp, SW2);

    // SW2[s] <- (batch-total - SW2[s]) / dc   (LOO mean @ W2^T, by linearity)
    finalize_kernel<<<NB, 256, 0, stream>>>(SW2, cnt);

    // out = outp[0] + outp[1] + bias + SW2[seg]
    epilogue_kernel<<<(size_t)N_SAMPLES * PDIM / 4 / 256, 256, 0, stream>>>(
        out, outp, SW2, bias, seg);
}

// Round 10
// 286.861 us; speedup vs baseline: 1.1957x; 1.1257x over previous
//
#include <hip/hip_runtime.h>
#include <cstdint>

#define N_SAMPLES 16384
#define DIM 2048
#define PDIM 256
#define NB 32
#define NL 100
#define NSEG (NB * NL)

typedef float floatx4 __attribute__((ext_vector_type(4)));
typedef __bf16 bf16x8 __attribute__((ext_vector_type(8)));

__device__ __forceinline__ unsigned short f32_to_bf16(float f) {
    unsigned int u = __float_as_uint(f);
    u += 0x7fffu + ((u >> 16) & 1u);   // round-to-nearest-even
    return (unsigned short)(u >> 16);
}

// ---------------------------------------------------------------------------
// prep: Wbf = [W1;W2] -> bf16 (512x2048), bias sum, seg index, zero cnt + SW2
// ---------------------------------------------------------------------------
__global__ __launch_bounds__(256) void prep_kernel(
    const float* __restrict__ W1w, const float* __restrict__ W1b,
    const float* __restrict__ W2w, const float* __restrict__ W2b,
    const int* __restrict__ label, const int* __restrict__ lbatch,
    unsigned short* __restrict__ Wbf, float* __restrict__ bias,
    int* __restrict__ seg, int* __restrict__ cnt, float* __restrict__ SW2)
{
    int i = blockIdx.x * 256 + threadIdx.x;   // grid = PDIM*DIM threads
    Wbf[i]              = f32_to_bf16(W1w[i]);
    Wbf[PDIM * DIM + i] = f32_to_bf16(W2w[i]);
    if (i < PDIM) bias[i] = W1b[i] + W2b[i];
    if (i < N_SAMPLES) seg[i] = lbatch[i] * NL + label[i];
    if (i < NSEG) cnt[i] = 0;
    if (i < NSEG * PDIM / 2) ((float2*)SW2)[i] = make_float2(0.f, 0.f);
}

__global__ __launch_bounds__(256) void hist_kernel(
    const int* __restrict__ seg, int* __restrict__ cnt)
{
    int i = blockIdx.x * 256 + threadIdx.x;
    atomicAdd(&cnt[seg[i]], 1);
}

// ---------------------------------------------------------------------------
// GEMM, f32-A edition (xconv pass DELETED):
//   C[16384, 512] = x(f32) @ [W1;W2](bf16)^T,  BM=128, BN=128, BK=32.
// A is staged as f32 via global_load_lds (per-lane global addr), converted
// to bf16 in-register at fragment read (native casts -> v_cvt_pk_bf16_f32).
// A-tile [128][32]f32 has 128B row stride = 16-way bank conflict, fixed by
// rule-#21 XOR swizzle: linear LDS dest + inverse-swizzled SOURCE chunk
// (achk = (lane&7)^(lane>>3)) + same XOR on the read (chunk ^= row&7).
// Post-swizzle read spread = 2-way (free, m136).
// grid = (128, 4): 512 WGs, full K per block (R6 config — measured faster
// than split-K in R9). cols 0..255 (W1): out = acc + bias (coalesced);
// cols 256..511 (W2): atomicAdd(SW2[seg[row]]) — linearity: segment sums.
// ---------------------------------------------------------------------------
__global__ __launch_bounds__(256) void gemm512_kernel(
    const float* __restrict__ x,             // [16384,2048] f32
    const unsigned short* __restrict__ Wbf,  // [512,2048] bf16
    const float* __restrict__ bias, const int* __restrict__ seg,
    float* __restrict__ out, float* __restrict__ SW2)
{
    constexpr int BM = 128, BN = 128, BK = 32;
    __shared__ __align__(16) float ldsAf[BM * BK];           // 16 KB f32
    __shared__ __align__(16) unsigned short ldsB[BN * BK];   // 8 KB bf16
    const int tid = threadIdx.x;
    const int lane = tid & 63;
    const int wave = tid >> 6;
    const int wr = wave >> 1, wc = wave & 1;   // 2x2 waves, 64x64 subtile
    const int quad = lane >> 4, l15 = lane & 15;
    const int m0 = blockIdx.x * BM;
    const int n0 = blockIdx.y * BN;            // 0,128,256,384

    // A staging: 8 rows / gload_lds inst; lane -> (row = lane>>3, 16B chunk).
    // Source chunk is XOR-swizzled so the linear LDS fill lands swizzled.
    const int arow = lane >> 3;                // 0..7
    const int achk = (lane & 7) ^ arow;        // inverse-swizzled source chunk
    // B staging: 16 rows / inst (bf16, m97 layout unchanged)
    const int brow = lane >> 2, bchk = lane & 3;

    floatx4 acc[4][4];
    #pragma unroll
    for (int i = 0; i < 4; ++i)
        #pragma unroll
        for (int j = 0; j < 4; ++j) acc[i][j] = (floatx4){0.f, 0.f, 0.f, 0.f};

    const float* Asrc = x + (size_t)(m0 + arow) * DIM + achk * 4;
    const unsigned short* Bsrc = Wbf + (size_t)(n0 + brow) * DIM + bchk * 8;

    for (int kk = 0; kk < DIM; kk += BK) {
        __syncthreads();
        #pragma unroll
        for (int ch = wave; ch < 16; ch += 4)      // A: 16 insts, 8 rows each
            __builtin_amdgcn_global_load_lds(
                (const __attribute__((address_space(1))) void*)(Asrc + (size_t)ch * 8 * DIM + kk),
                (__attribute__((address_space(3))) void*)&ldsAf[ch * 256], 16, 0, 0);
        #pragma unroll
        for (int ch = wave; ch < 8; ch += 4)       // B: 8 insts, 16 rows each
            __builtin_amdgcn_global_load_lds(
                (const __attribute__((address_space(1))) void*)(Bsrc + (size_t)ch * 16 * DIM + kk),
                (__attribute__((address_space(3))) void*)&ldsB[ch * 512], 16, 0, 0);
        __syncthreads();

        bf16x8 af[4], bf[4];
        #pragma unroll
        for (int mi = 0; mi < 4; ++mi) {
            const int ar = wr * 64 + mi * 16 + l15;
            const int s = ar & 7;                  // read-side XOR swizzle
            const float* pa = &ldsAf[ar * BK];
            floatx4 lo = *(const floatx4*)(pa + (((quad * 2)     ^ s) << 2));
            floatx4 hi = *(const floatx4*)(pa + (((quad * 2 + 1) ^ s) << 2));
            af[mi] = (bf16x8){ (__bf16)lo[0], (__bf16)lo[1], (__bf16)lo[2], (__bf16)lo[3],
                               (__bf16)hi[0], (__bf16)hi[1], (__bf16)hi[2], (__bf16)hi[3] };
        }
        #pragma unroll
        for (int ni = 0; ni < 4; ++ni)
            bf[ni] = *(const bf16x8*)&ldsB[(wc * 64 + ni * 16 + l15) * BK + quad * 8];
        #pragma unroll
        for (int mi = 0; mi < 4; ++mi)
            #pragma unroll
            for (int ni = 0; ni < 4; ++ni)
                acc[mi][ni] = __builtin_amdgcn_mfma_f32_16x16x32_bf16(
                    af[mi], bf[ni], acc[mi][ni], 0, 0, 0);
    }

    if (n0 < PDIM) {                           // W1 half -> out + bias
        #pragma unroll
        for (int mi = 0; mi < 4; ++mi) {
            const int rbase = m0 + wr * 64 + mi * 16 + quad * 4;
            #pragma unroll
            for (int ni = 0; ni < 4; ++ni) {
                const int col = n0 + wc * 64 + ni * 16 + l15;
                const float bs = bias[col];
                #pragma unroll
                for (int r = 0; r < 4; ++r)
                    out[(size_t)(rbase + r) * PDIM + col] = acc[mi][ni][r] + bs;
            }
        }
    } else {                                   // W2 half -> SW2[seg] atomics
        const int c0 = n0 - PDIM;
        #pragma unroll
        for (int mi = 0; mi < 4; ++mi) {
            const int rbase = m0 + wr * 64 + mi * 16 + quad * 4;
            #pragma unroll
            for (int r = 0; r < 4; ++r) {
                const int sr = seg[rbase + r];
                #pragma unroll
                for (int ni = 0; ni < 4; ++ni) {
                    const int col = c0 + wc * 64 + ni * 16 + l15;
                    atomicAdd(&SW2[(size_t)sr * PDIM + col], acc[mi][ni][r]);
                }
            }
        }
    }
}

// ---------------------------------------------------------------------------
// finalize: SW2[s,col] <- (BW2[b,col] - SW2[s,col]) / dc   (in place)
// BW2[b] = sum over the batch's 100 label-rows of SW2 (linearity),
// dc = batch count - segment count (zero-guarded like the reference).
// ---------------------------------------------------------------------------
__global__ __launch_bounds__(256) void finalize_kernel(
    float* __restrict__ SW2, const int* __restrict__ cnt)
{
    const int b = blockIdx.x;        // 0..31
    const int col = threadIdx.x;     // 0..255
    int cb = 0;
    #pragma unroll 4
    for (int l = 0; l < NL; ++l) cb += cnt[b * NL + l];
    float tot = 0.f;
    #pragma unroll 4
    for (int l = 0; l < NL; ++l)
        tot += SW2[(size_t)(b * NL + l) * PDIM + col];
    for (int l = 0; l < NL; ++l) {
        const int s = b * NL + l;
        const int dc = cb - cnt[s];
        const float v = SW2[(size_t)s * PDIM + col];
        SW2[(size_t)s * PDIM + col] = (dc > 0) ? (tot - v) / (float)dc : 0.f;
    }
}

// ---------------------------------------------------------------------------
// epilogue: out[i,:] += SW2[seg[i],:]   (bias already added in the GEMM)
// ---------------------------------------------------------------------------
__global__ __launch_bounds__(256) void epilogue_kernel(
    float* __restrict__ out, const float* __restrict__ SW2,
    const int* __restrict__ seg)
{
    const int idx = blockIdx.x * 256 + threadIdx.x;   // over N*PDIM/4
    const int row = idx >> 6;                         // 64 float4 per row
    const int c = (idx & 63) * 4;
    float4 v = ((const float4*)out)[idx];
    const float4 s4 = *(const float4*)&SW2[(size_t)seg[row] * PDIM + c];
    v.x += s4.x; v.y += s4.y; v.z += s4.z; v.w += s4.w;
    ((float4*)out)[idx] = v;
}

// ---------------------------------------------------------------------------
extern "C" void kernel_launch(void* const* d_in, const int* in_sizes, int n_in,
                              void* d_out, int out_size, void* d_ws, size_t ws_size,
                              hipStream_t stream)
{
    const float* x      = (const float*)d_in[0];
    const int*   label  = (const int*)d_in[1];
    const int*   lbatch = (const int*)d_in[2];
    const float* W1w    = (const float*)d_in[3];
    const float* W1b    = (const float*)d_in[4];
    const float* W2w    = (const float*)d_in[5];
    const float* W2b    = (const float*)d_in[6];
    float* out = (float*)d_out;

    char* ws = (char*)d_ws;
    size_t off = 0;
    auto alloc = [&](size_t bytes) {
        void* p = ws + off;
        off = (off + bytes + 255) & ~(size_t)255;
        return p;
    };
    unsigned short* Wbf = (unsigned short*)alloc((size_t)2 * PDIM * DIM * 2);  // 2 MB
    float* SW2  = (float*)alloc((size_t)NSEG * PDIM * 4);                      // 3.3 MB
    float* bias = (float*)alloc(PDIM * 4);
    int*   seg  = (int*)alloc(N_SAMPLES * 4);
    int*   cnt  = (int*)alloc(NSEG * 4);

    prep_kernel<<<PDIM * DIM / 256, 256, 0, stream>>>(
        W1w, W1b, W2w, W2b, label, lbatch, Wbf, bias, seg, cnt, SW2);

    hist_kernel<<<N_SAMPLES / 256, 256, 0, stream>>>(seg, cnt);

    // out = x@W1^T + bias (n-tiles 0,1) ; SW2[s] += x@W2^T segment rows (2,3)
    gemm512_kernel<<<dim3(N_SAMPLES / 128, 4), 256, 0, stream>>>(
        x, Wbf, bias, seg, out, SW2);

    // SW2[s] <- (batch-total - SW2[s]) / dc   (LOO mean @ W2^T, by linearity)
    finalize_kernel<<<NB, 256, 0, stream>>>(SW2, cnt);

    // out += SW2[seg]
    epilogue_kernel<<<(size_t)N_SAMPLES * PDIM / 4 / 256, 256, 0, stream>>>(
        out, SW2, seg);
}

// Round 11
// 271.527 us; speedup vs baseline: 1.2632x; 1.0565x over previous
//
#include <hip/hip_runtime.h>
#include <cstdint>

#define N_SAMPLES 16384
#define DIM 2048
#define PDIM 256
#define NB 32
#define NL 100
#define NSEG (NB * NL)

typedef float floatx4 __attribute__((ext_vector_type(4)));
typedef __bf16 bf16x8 __attribute__((ext_vector_type(8)));

__device__ __forceinline__ unsigned short f32_to_bf16(float f) {
    unsigned int u = __float_as_uint(f);
    u += 0x7fffu + ((u >> 16) & 1u);   // round-to-nearest-even
    return (unsigned short)(u >> 16);
}

// ---------------------------------------------------------------------------
// prep: Wbf = [W1;W2] -> bf16 (512x2048), bias sum, seg index, zero cnt + SW2
// ---------------------------------------------------------------------------
__global__ __launch_bounds__(256) void prep_kernel(
    const float* __restrict__ W1w, const float* __restrict__ W1b,
    const float* __restrict__ W2w, const float* __restrict__ W2b,
    const int* __restrict__ label, const int* __restrict__ lbatch,
    unsigned short* __restrict__ Wbf, float* __restrict__ bias,
    int* __restrict__ seg, int* __restrict__ cnt, float* __restrict__ SW2)
{
    int i = blockIdx.x * 256 + threadIdx.x;   // grid = PDIM*DIM threads
    Wbf[i]              = f32_to_bf16(W1w[i]);
    Wbf[PDIM * DIM + i] = f32_to_bf16(W2w[i]);
    if (i < PDIM) bias[i] = W1b[i] + W2b[i];
    if (i < N_SAMPLES) seg[i] = lbatch[i] * NL + label[i];
    if (i < NSEG) cnt[i] = 0;
    if (i < NSEG * PDIM / 2) ((float2*)SW2)[i] = make_float2(0.f, 0.f);
}

__global__ __launch_bounds__(256) void hist_kernel(
    const int* __restrict__ seg, int* __restrict__ cnt)
{
    int i = blockIdx.x * 256 + threadIdx.x;
    atomicAdd(&cnt[seg[i]], 1);
}

// ---------------------------------------------------------------------------
// GEMM, f32-A, BM=64 BN=128 BK=64:
//   C[16384, 512] = x(f32) @ [W1;W2](bf16)^T
// grid = (256, 4) = 1024 WGs = 4 blocks/CU (16 waves/CU TLP), 32 K-steps
// (half of R10's 64 -> half the vmcnt(0) barrier drains).
// LDS 32 KB: A 64x64 f32 (16 KB) + B 128x64 bf16 (16 KB).
// Both operands staged via global_load_lds with SOURCE-side XOR swizzle
// (rule #21: linear LDS dest + inverse-swizzled per-lane source + same XOR
// on the read). Key = row&7; verified: writer lane stores k-chunk
// c^(row&7) at LDS chunk c, reader fetches chunk q^(row&7) -> k-chunk q.
// This keeps every b128 fragment read at the 8-lane/bank-group optimum
// (rows are bank-aligned at 64-elem stride; unswizzled would be 16-way).
// cols 0..255 (W1): out = acc + bias (coalesced stores)
// cols 256..511 (W2): atomicAdd(SW2[seg[row]]) — linearity: segment sums.
// ---------------------------------------------------------------------------
__global__ __launch_bounds__(256, 4) void gemm512_kernel(
    const float* __restrict__ x,             // [16384,2048] f32
    const unsigned short* __restrict__ Wbf,  // [512,2048] bf16
    const float* __restrict__ bias, const int* __restrict__ seg,
    float* __restrict__ out, float* __restrict__ SW2)
{
    constexpr int BM = 64, BN = 128, BK = 64;
    __shared__ __align__(16) float ldsAf[BM * BK];           // 16 KB f32
    __shared__ __align__(16) unsigned short ldsB[BN * BK];   // 16 KB bf16
    const int tid = threadIdx.x;
    const int lane = tid & 63;
    const int wave = tid >> 6;                 // WR=1, WC=4: wave = n-group
    const int quad = lane >> 4, l15 = lane & 15;
    const int m0 = blockIdx.x * BM;
    const int n0 = blockIdx.y * BN;            // 0,128,256,384

    // A staging: 16 insts (4/wave), 4 rows/inst (64 lanes x 16B / 256B row).
    // lane -> (row_off = lane>>4, LDS chunk = lane&15). Source k-chunk is
    // (lane&15) ^ (row&7); row&7 = 4*(ch&1) + (lane>>4), ch&1 == wave&1 for
    // ch in {wave, wave+4, wave+8, wave+12}.
    const int arow = lane >> 4;                                  // 0..3
    const int achk = (lane & 15) ^ ((wave & 1) * 4 + arow);      // src chunk
    // B staging: 16 insts (4/wave), 8 rows/inst (128B row).
    // row&7 = lane>>3 (ch*8 == 0 mod 8) -> constant per-lane source chunk.
    const int brow = lane >> 3;                                  // 0..7
    const int bchk = (lane & 7) ^ brow;                          // src chunk

    floatx4 acc[4][2];
    #pragma unroll
    for (int i = 0; i < 4; ++i)
        #pragma unroll
        for (int j = 0; j < 2; ++j) acc[i][j] = (floatx4){0.f, 0.f, 0.f, 0.f};

    const float* Asrc = x + (size_t)(m0 + arow) * DIM + achk * 4;
    const unsigned short* Bsrc = Wbf + (size_t)(n0 + brow) * DIM + bchk * 8;

    const int swa = l15 & 7;                   // read-side XOR key (=row&7)

    for (int kk = 0; kk < DIM; kk += BK) {
        __syncthreads();
        #pragma unroll
        for (int ch = wave; ch < 16; ch += 4)      // A: 4 rows/inst
            __builtin_amdgcn_global_load_lds(
                (const __attribute__((address_space(1))) void*)(Asrc + (size_t)ch * 4 * DIM + kk),
                (__attribute__((address_space(3))) void*)&ldsAf[ch * 256], 16, 0, 0);
        #pragma unroll
        for (int ch = wave; ch < 16; ch += 4)      // B: 8 rows/inst
            __builtin_amdgcn_global_load_lds(
                (const __attribute__((address_space(1))) void*)(Bsrc + (size_t)ch * 8 * DIM + kk),
                (__attribute__((address_space(3))) void*)&ldsB[ch * 512], 16, 0, 0);
        __syncthreads();

        #pragma unroll
        for (int ks = 0; ks < 2; ++ks) {           // two 32-wide K sub-steps
            bf16x8 af[4], bf[2];
            #pragma unroll
            for (int mi = 0; mi < 4; ++mi) {       // A rows mi*16 + l15
                const int ar = mi * 16 + l15;
                const int q0 = ks * 8 + quad * 2;  // 16B k-chunk pair
                const float* pa = &ldsAf[ar * BK];
                floatx4 lo = *(const floatx4*)(pa + (((q0)     ^ swa) << 2));
                floatx4 hi = *(const floatx4*)(pa + (((q0 + 1) ^ swa) << 2));
                af[mi] = (bf16x8){ (__bf16)lo[0], (__bf16)lo[1], (__bf16)lo[2], (__bf16)lo[3],
                                   (__bf16)hi[0], (__bf16)hi[1], (__bf16)hi[2], (__bf16)hi[3] };
            }
            #pragma unroll
            for (int ni = 0; ni < 2; ++ni) {       // B rows wave*32+ni*16+l15
                const int br = wave * 32 + ni * 16 + l15;
                const int q = ks * 4 + quad;       // 16B k-chunk
                bf[ni] = *(const bf16x8*)&ldsB[br * BK + (((q) ^ swa) << 3)];
            }
            #pragma unroll
            for (int mi = 0; mi < 4; ++mi)
                #pragma unroll
                for (int ni = 0; ni < 2; ++ni)
                    acc[mi][ni] = __builtin_amdgcn_mfma_f32_16x16x32_bf16(
                        af[mi], bf[ni], acc[mi][ni], 0, 0, 0);
        }
    }

    if (n0 < PDIM) {                           // W1 half -> out + bias
        #pragma unroll
        for (int mi = 0; mi < 4; ++mi) {
            const int rbase = m0 + mi * 16 + quad * 4;
            #pragma unroll
            for (int ni = 0; ni < 2; ++ni) {
                const int col = n0 + wave * 32 + ni * 16 + l15;
                const float bs = bias[col];
                #pragma unroll
                for (int r = 0; r < 4; ++r)
                    out[(size_t)(rbase + r) * PDIM + col] = acc[mi][ni][r] + bs;
            }
        }
    } else {                                   // W2 half -> SW2[seg] atomics
        const int c0 = n0 - PDIM;
        #pragma unroll
        for (int mi = 0; mi < 4; ++mi) {
            const int rbase = m0 + mi * 16 + quad * 4;
            #pragma unroll
            for (int r = 0; r < 4; ++r) {
                const int sr = seg[rbase + r];
                #pragma unroll
                for (int ni = 0; ni < 2; ++ni) {
                    const int col = c0 + wave * 32 + ni * 16 + l15;
                    atomicAdd(&SW2[(size_t)sr * PDIM + col], acc[mi][ni][r]);
                }
            }
        }
    }
}

// ---------------------------------------------------------------------------
// finalize: SW2[s,col] <- (BW2[b,col] - SW2[s,col]) / dc   (in place)
// BW2[b] = sum over the batch's 100 label-rows of SW2 (linearity),
// dc = batch count - segment count (zero-guarded like the reference).
// ---------------------------------------------------------------------------
__global__ __launch_bounds__(256) void finalize_kernel(
    float* __restrict__ SW2, const int* __restrict__ cnt)
{
    const int b = blockIdx.x;        // 0..31
    const int col = threadIdx.x;     // 0..255
    int cb = 0;
    #pragma unroll 4
    for (int l = 0; l < NL; ++l) cb += cnt[b * NL + l];
    float tot = 0.f;
    #pragma unroll 4
    for (int l = 0; l < NL; ++l)
        tot += SW2[(size_t)(b * NL + l) * PDIM + col];
    for (int l = 0; l < NL; ++l) {
        const int s = b * NL + l;
        const int dc = cb - cnt[s];
        const float v = SW2[(size_t)s * PDIM + col];
        SW2[(size_t)s * PDIM + col] = (dc > 0) ? (tot - v) / (float)dc : 0.f;
    }
}

// ---------------------------------------------------------------------------
// epilogue: out[i,:] += SW2[seg[i],:]   (bias already added in the GEMM)
// ---------------------------------------------------------------------------
__global__ __launch_bounds__(256) void epilogue_kernel(
    float* __restrict__ out, const float* __restrict__ SW2,
    const int* __restrict__ seg)
{
    const int idx = blockIdx.x * 256 + threadIdx.x;   // over N*PDIM/4
    const int row = idx >> 6;                         // 64 float4 per row
    const int c = (idx & 63) * 4;
    float4 v = ((const float4*)out)[idx];
    const float4 s4 = *(const float4*)&SW2[(size_t)seg[row] * PDIM + c];
    v.x += s4.x; v.y += s4.y; v.z += s4.z; v.w += s4.w;
    ((float4*)out)[idx] = v;
}

// ---------------------------------------------------------------------------
extern "C" void kernel_launch(void* const* d_in, const int* in_sizes, int n_in,
                              void* d_out, int out_size, void* d_ws, size_t ws_size,
                              hipStream_t stream)
{
    const float* x      = (const float*)d_in[0];
    const int*   label  = (const int*)d_in[1];
    const int*   lbatch = (const int*)d_in[2];
    const float* W1w    = (const float*)d_in[3];
    const float* W1b    = (const float*)d_in[4];
    const float* W2w    = (const float*)d_in[5];
    const float* W2b    = (const float*)d_in[6];
    float* out = (float*)d_out;

    char* ws = (char*)d_ws;
    size_t off = 0;
    auto alloc = [&](size_t bytes) {
        void* p = ws + off;
        off = (off + bytes + 255) & ~(size_t)255;
        return p;
    };
    unsigned short* Wbf = (unsigned short*)alloc((size_t)2 * PDIM * DIM * 2);  // 2 MB
    float* SW2  = (float*)alloc((size_t)NSEG * PDIM * 4);                      // 3.3 MB
    float* bias = (float*)alloc(PDIM * 4);
    int*   seg  = (int*)alloc(N_SAMPLES * 4);
    int*   cnt  = (int*)alloc(NSEG * 4);

    prep_kernel<<<PDIM * DIM / 256, 256, 0, stream>>>(
        W1w, W1b, W2w, W2b, label, lbatch, Wbf, bias, seg, cnt, SW2);

    hist_kernel<<<N_SAMPLES / 256, 256, 0, stream>>>(seg, cnt);

    // out = x@W1^T + bias (n-tiles 0,1) ; SW2[s] += x@W2^T segment rows (2,3)
    gemm512_kernel<<<dim3(N_SAMPLES / 64, 4), 256, 0, stream>>>(
        x, Wbf, bias, seg, out, SW2);

    // SW2[s] <- (batch-total - SW2[s]) / dc   (LOO mean @ W2^T, by linearity)
    finalize_kernel<<<NB, 256, 0, stream>>>(SW2, cnt);

    // out += SW2[seg]
    epilogue_kernel<<<(size_t)N_SAMPLES * PDIM / 4 / 256, 256, 0, stream>>>(
        out, SW2, seg);
}